// Round 12
// baseline (194.266 us; speedup 1.0000x reference)
//
#include <hip/hip_runtime.h>

// VectorQuantizer, single-term fp16 MFMA, in-block split-K, 8-wave blocks.
// scores = -2*E@C^T + ||c||^2; argmin_k; gather; mse losses.
//   eh = fp16(-2e), ch = fp16(1024c); acc = eh@ch (fp32 MFMA, C-init = 1024*||c||^2)
//   scaled score = acc ; real = acc * 2^-10. Dropped-term err sigma ~3e-6 << MARGIN.
// Block = 512 thr (8 waves) x 128 rows; grid 512 -> 4 blocks/CU, 32 waves/CU
// (2x main8's TLP at IDENTICAL per-wave code & HALF the L2 staging traffic:
// each 8KB tile is shared by 4 row-waves instead of 2).
// Wave (rw,pair): rw=w&3 owns rows rw*32..+31, pair=w>>2 sweeps k-half.
// Codebook tiles stream via global_load_lds (16KB/step), dbuf'd, 16 steps.
// __launch_bounds__(512,8) pins VGPR<=64 (main8 measured 60) for 8 waves/SIMD.
// Rows whose top-2 gap < MARGIN get an exact fp32 rescan (vq_fix).
// Output: [0,N) idx as float | [N,N+N*D) quantized | +0,1,2 = vq,embed,commit.

#define NROWS 65536
#define KCB   1024
#define DIM   128
#define DV    32
#define MSE_DENOM 8388608.0f
#define MARGIN 3.0e-5f
#define MARGINS 0.030720f   // MARGIN * 1024 (scaled domain)
#define FLAGCAP 16384
#define CSCALE   1024.0f
#define CDESCALE 0.0009765625f

// ws byte layout
#define WS_CNORM_F  256     // float index: raw cnorm[1024] at byte 1024
#define WS_CN1024_F 1280    // float index: 1024*cnorm[1024] at byte 5120
#define WS_LIST_B   12288   // 16384 ints
#define WS_PH_B     77824   // 262144 B packed codebook frags (fp16)
#define WS_NEEDED   339968

typedef __attribute__((ext_vector_type(16))) float float16v;
typedef _Float16 half8 __attribute__((ext_vector_type(8)));
union U4H8 { uint4 u; half8 h; };
union F4A  { float4 v; float f[4]; };
union F16V { float16v v; float f[16]; };
union HU   { _Float16 f; unsigned short u; };

__device__ __forceinline__ float fmed3(float a, float b, float c) {
  return __builtin_amdgcn_fmed3f(a, b, c);
}
__device__ __forceinline__ void gload16(const void* g, void* s) {
  __builtin_amdgcn_global_load_lds((const __attribute__((address_space(1))) unsigned int*)g,
                                   (__attribute__((address_space(3))) unsigned int*)s,
                                   16, 0, 0);
}

// ---------- fused prep (cnorm + zero) & pack (frag-linear fp16 of 1024*c) ----
// blocks [0,64): pack slot g = b*256+t; blocks [64,68): cnorm k = (b-64)*256+t.
// pack layout: g: mt=g>>9, s=(g>>6)&7, l=g&63 ; value j:
//   C[mt*32+(l&31)][s*16+(l>>5)*8+j]
__global__ __launch_bounds__(256) void vq_prep_pack(const float* __restrict__ C,
                                                    float* __restrict__ wsf,
                                                    uint4* __restrict__ PH) {
  const int b = blockIdx.x;
  if (b < 64) {
    int g = b * 256 + threadIdx.x;
    int mt = g >> 9, s = (g >> 6) & 7, l = g & 63;
    int cw = mt * 32 + (l & 31);
    int k0 = s * 16 + (l >> 5) * 8;
    const float* src = C + (size_t)cw * DIM + k0;
    float4 x0 = *(const float4*)src;
    float4 x1 = *(const float4*)(src + 4);
    unsigned h[8];
    {
      float v[8] = {x0.x, x0.y, x0.z, x0.w, x1.x, x1.y, x1.z, x1.w};
#pragma unroll
      for (int j = 0; j < 8; ++j) { HU u; u.f = (_Float16)(CSCALE * v[j]); h[j] = u.u; }
    }
    PH[g] = make_uint4(h[0] | (h[1] << 16), h[2] | (h[3] << 16),
                       h[4] | (h[5] << 16), h[6] | (h[7] << 16));
  } else {
    int k = (b - 64) * 256 + threadIdx.x;   // 4 blocks x 256 == 1024
    if (k == 0) { wsf[0] = 0.0f; ((unsigned*)wsf)[1] = 0u; }
    const float4* c4 = (const float4*)C + (size_t)k * DV;
    float s = 0.f;
#pragma unroll 8
    for (int i = 0; i < DV; ++i) {
      float4 v = c4[i];
      s = fmaf(v.x, v.x, s); s = fmaf(v.y, v.y, s);
      s = fmaf(v.z, v.z, s); s = fmaf(v.w, v.w, s);
    }
    wsf[WS_CNORM_F + k]  = s;
    wsf[WS_CN1024_F + k] = s * CSCALE;
  }
}

// ---------- main: 8-wave blocks, in-block split-K, in-block gather ----------
__global__ __launch_bounds__(512, 8) void vq_main13(const float* __restrict__ E,
                                                    const float* __restrict__ C,
                                                    float* __restrict__ wsf,
                                                    float* __restrict__ out) {
  __shared__ uint4 SH[2][1024];              // [buf][pair*512 + slot], 16KB/buf
  __shared__ __align__(16) float CN[1024];   // 1024*||c||^2
  __shared__ float X1[128], X2[128];         // cross-pair merge: best/second
  __shared__ int   XI[128];
  __shared__ int   BI[128];

  const int tid  = threadIdx.x;              // 0..511 (8 waves)
  const int w    = tid >> 6;                 // wave 0..7
  const int l    = tid & 63;
  const int half = l >> 5;
  const int rr   = l & 31;
  const int pair = w >> 2;                   // 0: k<512, 1: k>=512
  const int rw   = w & 3;                    // row sub-block 0..3
  const int row0 = blockIdx.x * 128;
  const int row  = row0 + rw * 32 + rr;

  const uint4* PHg = (const uint4*)((const char*)wsf + WS_PH_B);

  // ---- issue async stage of step-0 tiles (tg 0 and 16) + CN ----
  {
    uint4* base = &SH[0][0];
    gload16(PHg + tid,            base + tid);          // pair0 tile 0
    gload16(PHg + 16 * 512 + tid, base + 512 + tid);    // pair1 tile 16
    if (tid < 256)
      gload16(((const uint4*)(wsf + WS_CN1024_F)) + tid, ((uint4*)CN) + tid);
  }

  // ---- load this wave's 32 rows into register B-frags (single fp16 term) ----
  // lane (rr,half) covers dims {s*16 + half*8 .. +7} for s=0..7  (64 floats)
  half8 beh[8];
  float s2 = 0.f;
  const float* erow = E + (size_t)row * DIM + half * 8;
#pragma unroll
  for (int s = 0; s < 8; ++s) {
    float4 x0 = *(const float4*)(erow + s * 16);
    float4 x1 = *(const float4*)(erow + s * 16 + 4);
    float v[8] = {x0.x, x0.y, x0.z, x0.w, x1.x, x1.y, x1.z, x1.w};
#pragma unroll
    for (int j = 0; j < 8; ++j) {
      float y = v[j];
      s2 = fmaf(y, y, s2);
      beh[s][j] = (_Float16)(-2.f * y);
    }
  }

  asm volatile("s_waitcnt vmcnt(0)" ::: "memory");
  __syncthreads();

  float m1 = 3.0e38f, m2 = 3.0e38f;          // scaled best / second
  int   bi = 0;                              // best index (absolute)

  for (int st = 0; st < 16; ++st) {
    const int buf = st & 1;
    const int tg  = pair * 16 + st;
    // stage next step's two tiles (async; 1 gload16 per thread per tile)
    if (st < 15) {
      uint4* nb = &SH[buf ^ 1][0];
      const uint4* s0 = PHg + (size_t)(st + 1) * 512;
      const uint4* s1 = PHg + (size_t)(17 + st) * 512;
      gload16(s0 + tid, nb + tid);
      gload16(s1 + tid, nb + 512 + tid);
    }

    // two 4-deep MFMA chains; accA initialized with 1024*||c||^2
    F16V accA, accB;
#pragma unroll
    for (int q = 0; q < 4; ++q) {
      F4A c; c.v = *(const float4*)&CN[tg * 32 + q * 8 + half * 4];
      accA.f[q * 4 + 0] = c.f[0]; accA.f[q * 4 + 1] = c.f[1];
      accA.f[q * 4 + 2] = c.f[2]; accA.f[q * 4 + 3] = c.f[3];
    }
    accB.v = (float16v){0,0,0,0,0,0,0,0,0,0,0,0,0,0,0,0};
#pragma unroll
    for (int s = 0; s < 8; s += 2) {
      U4H8 h0, h1;
      h0.u = SH[buf][pair * 512 + s * 64 + l];
      h1.u = SH[buf][pair * 512 + (s + 1) * 64 + l];
      accA.v = __builtin_amdgcn_mfma_f32_32x32x16_f16(h0.h, beh[s],     accA.v, 0, 0, 0);
      accB.v = __builtin_amdgcn_mfma_f32_32x32x16_f16(h1.h, beh[s + 1], accB.v, 0, 0, 0);
    }

    // fold 16 scaled scores; k = tg*32 + half*4 + q*8 + i
    const int kb = tg * 32 + half * 4;
#pragma unroll
    for (int reg = 0; reg < 16; ++reg) {
      float sc = accA.f[reg] + accB.f[reg];
      bool nb_ = sc < m1;
      m2 = fmed3(sc, m1, m2);
      m1 = fminf(sc, m1);
      bi = nb_ ? (kb + (reg >> 2) * 8 + (reg & 3)) : bi;
    }

    asm volatile("s_waitcnt vmcnt(0)" ::: "memory");
    __syncthreads();
  }

  // ---- merge halves (lane l <-> l+32: same row, disjoint k subsets) ----
  {
    float om1 = __shfl_xor(m1, 32, 64);
    float om2 = __shfl_xor(m2, 32, 64);
    int   obi = __shfl_xor(bi, 32, 64);
    float nsv = fminf(fminf(m2, om2), fmaxf(m1, om1));
    if (om1 < m1 || (om1 == m1 && obi < bi)) { m1 = om1; bi = obi; }
    m2 = nsv;
  }
  float en = s2 + __shfl_xor(s2, 32, 64);

  // ---- cross-pair merge via LDS ----
  if (pair == 1 && half == 0) {
    X1[rw * 32 + rr] = m1; X2[rw * 32 + rr] = m2; XI[rw * 32 + rr] = bi;
  }
  __syncthreads();

  if (pair == 0 && half == 0) {
    const int r = rw * 32 + rr;
    float xb = X1[r], xs = X2[r];
    int   xi = XI[r];
    float sv = fminf(fminf(m2, xs), fmaxf(m1, xb));
    if (xb < m1 || (xb == m1 && xi < bi)) { m1 = xb; bi = xi; }
    out[row] = (float)bi;
    BI[r] = bi;
    if (sv - m1 < MARGINS) {
      unsigned idx = atomicAdd((unsigned*)wsf + 1, 1u);
      if (idx < FLAGCAP) ((int*)((char*)wsf + WS_LIST_B))[idx] = row;
    }
    float term = fmaf(m1, CDESCALE, en);
#pragma unroll
    for (int off = 16; off > 0; off >>= 1) term += __shfl_down(term, off);
    if (rr == 0) atomicAdd(wsf, term);
  }
  __syncthreads();

  // ---- gather quantized_st (128 rows x 32 float4) ----
  const float4* C4   = (const float4*)C;
  float4*       out4 = (float4*)out;
#pragma unroll
  for (int it = 0; it < 8; ++it) {
    int flat = it * 512 + tid;
    int r = flat >> 5, d4 = flat & 31;
    out4[(NROWS / 4) + (size_t)(row0 + r) * DV + d4] = C4[(size_t)BI[r] * DV + d4];
  }
}

// ---------- exact fp32 rescan of flagged rows (+ fused final scalars) --------
__global__ __launch_bounds__(256) void vq_fix(const float* __restrict__ E,
                                              const float* __restrict__ C,
                                              float* __restrict__ wsf,
                                              float* __restrict__ out) {
  __shared__ float4 eL[4][32];
  __shared__ float  RV[4][4];
  __shared__ int    RI[4][4];
  __shared__ int    RESi[4];
  const int tid = threadIdx.x;
  const int wv  = tid >> 6;
  const int ln  = tid & 63;

  // fused final scalars (wsf[0] complete after vq_main13)
  if (blockIdx.x == 0 && tid == 0) {
    float mse = wsf[0] / MSE_DENOM;
    out[NROWS + NROWS * DIM + 0] = 1.25f * mse;
    out[NROWS + NROWS * DIM + 1] = mse;
    out[NROWS + NROWS * DIM + 2] = mse;
  }

  const int* list = (const int*)((const char*)wsf + WS_LIST_B);
  int nf = (int)((const unsigned*)wsf)[1];
  if (nf > FLAGCAP) nf = FLAGCAP;
  const float4* E4 = (const float4*)E;
  const float4* C4 = (const float4*)C;
  const float*  cn = wsf + WS_CNORM_F;
  float4* out4 = (float4*)out;

  for (int g = blockIdx.x; g * 4 < nf; g += gridDim.x) {
    const int base = g * 4;
    if (tid < 128) {
      int r = tid >> 5, d4 = tid & 31;
      int R = (base + r < nf) ? list[base + r] : list[base];
      eL[r][d4] = E4[(size_t)R * DV + d4];
    }
    __syncthreads();
    float bv[4] = {3.0e38f, 3.0e38f, 3.0e38f, 3.0e38f};
    int   bi[4] = {0, 0, 0, 0};
#pragma unroll
    for (int j = 0; j < 4; ++j) {
      int k = j * 256 + tid;
      float d0 = 0.f, d1 = 0.f, d2 = 0.f, d3 = 0.f;
#pragma unroll 4
      for (int d4 = 0; d4 < 32; ++d4) {
        float4 c = C4[(size_t)k * DV + d4];
        float4 e0 = eL[0][d4], e1 = eL[1][d4], e2 = eL[2][d4], e3 = eL[3][d4];
        d0 = fmaf(c.x, e0.x, d0); d0 = fmaf(c.y, e0.y, d0);
        d0 = fmaf(c.z, e0.z, d0); d0 = fmaf(c.w, e0.w, d0);
        d1 = fmaf(c.x, e1.x, d1); d1 = fmaf(c.y, e1.y, d1);
        d1 = fmaf(c.z, e1.z, d1); d1 = fmaf(c.w, e1.w, d1);
        d2 = fmaf(c.x, e2.x, d2); d2 = fmaf(c.y, e2.y, d2);
        d2 = fmaf(c.z, e2.z, d2); d2 = fmaf(c.w, e2.w, d2);
        d3 = fmaf(c.x, e3.x, d3); d3 = fmaf(c.y, e3.y, d3);
        d3 = fmaf(c.z, e3.z, d3); d3 = fmaf(c.w, e3.w, d3);
      }
      float cnk = cn[k];
      float s0 = fmaf(-2.f, d0, cnk);
      float s1 = fmaf(-2.f, d1, cnk);
      float s2 = fmaf(-2.f, d2, cnk);
      float s3 = fmaf(-2.f, d3, cnk);
      if (s0 < bv[0] || (s0 == bv[0] && k < bi[0])) { bv[0] = s0; bi[0] = k; }
      if (s1 < bv[1] || (s1 == bv[1] && k < bi[1])) { bv[1] = s1; bi[1] = k; }
      if (s2 < bv[2] || (s2 == bv[2] && k < bi[2])) { bv[2] = s2; bi[2] = k; }
      if (s3 < bv[3] || (s3 == bv[3] && k < bi[3])) { bv[3] = s3; bi[3] = k; }
    }
#pragma unroll
    for (int off = 32; off > 0; off >>= 1) {
#pragma unroll
      for (int r = 0; r < 4; ++r) {
        float wv_ = __shfl_down(bv[r], off);
        int   ji  = __shfl_down(bi[r], off);
        if (wv_ < bv[r] || (wv_ == bv[r] && ji < bi[r])) { bv[r] = wv_; bi[r] = ji; }
      }
    }
    if (ln == 0) {
#pragma unroll
      for (int r = 0; r < 4; ++r) { RV[wv][r] = bv[r]; RI[wv][r] = bi[r]; }
    }
    __syncthreads();
    if (tid < 4) {
      float v = RV[0][tid]; int i = RI[0][tid];
#pragma unroll
      for (int q = 1; q < 4; ++q) {
        float vv = RV[q][tid]; int ii = RI[q][tid];
        if (vv < v || (vv == v && ii < i)) { v = vv; i = ii; }
      }
      RESi[tid] = i;
      if (base + tid < nf) out[list[base + tid]] = (float)i;
    }
    __syncthreads();
    if (tid < 128) {
      int r = tid >> 5, d4 = tid & 31;
      if (base + r < nf) {
        int R = list[base + r];
        out4[(NROWS / 4) + (size_t)R * DV + d4] = C4[(size_t)RESi[r] * DV + d4];
      }
    }
    __syncthreads();
  }
}

// ================= fallback (round-1 fp32 path, used if ws too small) ==========
__global__ __launch_bounds__(256) void vq_prep_fb(const float* __restrict__ C,
                                                  float* __restrict__ ws) {
  int k = blockIdx.x * 256 + threadIdx.x;
  if (k == 0) ws[0] = 0.0f;
  const float4* c4 = (const float4*)C + (size_t)k * DV;
  float s = 0.f;
#pragma unroll 8
  for (int i = 0; i < DV; ++i) {
    float4 v = c4[i];
    s = fmaf(v.x, v.x, s); s = fmaf(v.y, v.y, s);
    s = fmaf(v.z, v.z, s); s = fmaf(v.w, v.w, s);
  }
  ws[64 + k] = s;
}

__global__ __launch_bounds__(256) void vq_main_fb(const float* __restrict__ E,
                                                  const float* __restrict__ C,
                                                  const float* __restrict__ cnorm,
                                                  float* __restrict__ out,
                                                  float* __restrict__ lossacc) {
  __shared__ float smem[16384];
  float4* EsV = (float4*)smem;
  float4* CsV = (float4*)(smem + 8192);
  const int tid  = threadIdx.x;
  const int row0 = blockIdx.x * 64;
#pragma unroll
  for (int i = 0; i < 8; ++i) {
    int flat = i * 256 + tid;
    int r = flat >> 5, d4 = flat & 31;
    EsV[r * 32 + (d4 ^ (r & 31))] = ((const float4*)E)[(size_t)(row0 + r) * DV + d4];
  }
  const int tx = tid & 15, ty = tid >> 4;
  int rbase[4], rmask[4];
#pragma unroll
  for (int i = 0; i < 4; ++i) { int r = i * 16 + ty; rbase[i] = r * 32; rmask[i] = r & 31; }
  float bestv[4]; int besti[4];
#pragma unroll
  for (int i = 0; i < 4; ++i) { bestv[i] = 3.0e38f; besti[i] = 0; }
  for (int ch = 0; ch < 16; ++ch) {
    const int k0 = ch * 64;
    __syncthreads();
#pragma unroll
    for (int i = 0; i < 8; ++i) {
      int flat = i * 256 + tid;
      int k = flat >> 5, d4 = flat & 31;
      CsV[k * 32 + (d4 ^ (k & 31))] = ((const float4*)C)[(size_t)(k0 + k) * DV + d4];
    }
    __syncthreads();
    float acc[4][4] = {};
#pragma unroll 8
    for (int d4 = 0; d4 < DV; ++d4) {
      float4 a[4], b[4];
#pragma unroll
      for (int i = 0; i < 4; ++i) a[i] = EsV[rbase[i] + (d4 ^ rmask[i])];
#pragma unroll
      for (int j = 0; j < 4; ++j) { int k = j * 16 + tx; b[j] = CsV[k * 32 + (d4 ^ (k & 31))]; }
#pragma unroll
      for (int i = 0; i < 4; ++i)
#pragma unroll
        for (int j = 0; j < 4; ++j) {
          acc[i][j] = fmaf(a[i].x, b[j].x, acc[i][j]);
          acc[i][j] = fmaf(a[i].y, b[j].y, acc[i][j]);
          acc[i][j] = fmaf(a[i].z, b[j].z, acc[i][j]);
          acc[i][j] = fmaf(a[i].w, b[j].w, acc[i][j]);
        }
    }
#pragma unroll
    for (int j = 0; j < 4; ++j) {
      int kg = k0 + j * 16 + tx;
      float cnv = cnorm[kg];
#pragma unroll
      for (int i = 0; i < 4; ++i) {
        float s = fmaf(-2.0f, acc[i][j], cnv);
        if (s < bestv[i] || (s == bestv[i] && kg < besti[i])) { bestv[i] = s; besti[i] = kg; }
      }
    }
  }
  float* Rv = smem + 8192;
  int*   Ri = (int*)(smem + 9216);
  int*   BIf = (int*)(smem + 10240);
  __syncthreads();
#pragma unroll
  for (int i = 0; i < 4; ++i) {
    int r = i * 16 + ty;
    Rv[r * 16 + tx] = bestv[i];
    Ri[r * 16 + tx] = besti[i];
  }
  __syncthreads();
  if (tid < 64) {
    const int r = tid;
    float bv = Rv[r * 16]; int bi = Ri[r * 16];
#pragma unroll
    for (int t = 1; t < 16; ++t) {
      float v = Rv[r * 16 + t]; int ii = Ri[r * 16 + t];
      if (v < bv || (v == bv && ii < bi)) { bv = v; bi = ii; }
    }
    float en = 0.f;
#pragma unroll 8
    for (int d4 = 0; d4 < DV; ++d4) {
      float4 v = EsV[r * 32 + (d4 ^ (r & 31))];
      en = fmaf(v.x, v.x, en); en = fmaf(v.y, v.y, en);
      en = fmaf(v.z, v.z, en); en = fmaf(v.w, v.w, en);
    }
    out[row0 + r] = (float)bi;
    BIf[r] = bi;
    float blocksum = en + bv;
#pragma unroll
    for (int off = 32; off > 0; off >>= 1) blocksum += __shfl_down(blocksum, off);
    if (tid == 0) atomicAdd(lossacc, blocksum);
  }
  __syncthreads();
  const float4* C4   = (const float4*)C;
  float4*       out4 = (float4*)out;
  for (int flat = tid; flat < 64 * DV; flat += 256) {
    int r = flat >> 5, d4 = flat & 31;
    out4[(NROWS / 4) + (size_t)(row0 + r) * DV + d4] = C4[(size_t)BIf[r] * DV + d4];
  }
}

__global__ void vq_final_fb(const float* __restrict__ ws, float* __restrict__ out) {
  if (threadIdx.x == 0 && blockIdx.x == 0) {
    float mse = ws[0] / MSE_DENOM;
    out[NROWS + NROWS * DIM + 0] = 1.25f * mse;
    out[NROWS + NROWS * DIM + 1] = mse;
    out[NROWS + NROWS * DIM + 2] = mse;
  }
}

extern "C" void kernel_launch(void* const* d_in, const int* in_sizes, int n_in,
                              void* d_out, int out_size, void* d_ws, size_t ws_size,
                              hipStream_t stream) {
  const float* E = (const float*)d_in[0];
  const float* C = (const float*)d_in[1];
  float* out = (float*)d_out;
  float* wsf = (float*)d_ws;

  if (ws_size >= (size_t)WS_NEEDED) {
    uint4* PH = (uint4*)((char*)d_ws + WS_PH_B);
    vq_prep_pack<<<68, 256, 0, stream>>>(C, wsf, PH);
    vq_main13<<<NROWS / 128, 512, 0, stream>>>(E, C, wsf, out);
    vq_fix<<<512, 256, 0, stream>>>(E, C, wsf, out);
  } else {
    vq_prep_fb<<<4, 256, 0, stream>>>(C, wsf);
    vq_main_fb<<<NROWS / 64, 256, 0, stream>>>(E, C, wsf + 64, out, wsf);
    vq_final_fb<<<1, 64, 0, stream>>>(wsf, out);
  }
}

// Round 13
// 166.433 us; speedup vs baseline: 1.1672x; 1.1672x over previous
//
#include <hip/hip_runtime.h>

// VectorQuantizer, single-term fp16 MFMA, in-block split-K, 8-wave blocks.
// scores = -2*E@C^T + ||c||^2; argmin_k; gather; mse losses.
//   eh = fp16(-2e), ch = fp16(1024c); acc = eh@ch (fp32 MFMA, C-init = 1024*||c||^2)
//   scaled score = acc ; real = acc * 2^-10. Dropped-term err sigma ~3e-6 << MARGIN.
// Block = 512 thr (8 waves) x 128 rows; grid 512. __launch_bounds__(512,6):
// VGPR cap ~85 >> body's ~60 (round-12's (512,8) pinned VGPR=32 -> spill,
// WRITE 73MB; this round fixes ONLY that). 3 blocks/CU = 24 waves/CU at half
// main8's staging traffic (each 8KB tile shared by 4 row-waves).
// Wave (rw,pair): rw=w&3 owns rows rw*32..+31, pair=w>>2 sweeps k-half.
// Codebook tiles stream via global_load_lds (16KB/step), dbuf'd, 16 steps.
// Rows whose top-2 gap < MARGIN get an exact fp32 rescan (vq_fix).
// Output: [0,N) idx as float | [N,N+N*D) quantized | +0,1,2 = vq,embed,commit.

#define NROWS 65536
#define KCB   1024
#define DIM   128
#define DV    32
#define MSE_DENOM 8388608.0f
#define MARGIN 3.0e-5f
#define MARGINS 0.030720f   // MARGIN * 1024 (scaled domain)
#define FLAGCAP 16384
#define CSCALE   1024.0f
#define CDESCALE 0.0009765625f

// ws byte layout
#define WS_CNORM_F  256     // float index: raw cnorm[1024] at byte 1024
#define WS_CN1024_F 1280    // float index: 1024*cnorm[1024] at byte 5120
#define WS_LIST_B   12288   // 16384 ints
#define WS_PH_B     77824   // 262144 B packed codebook frags (fp16)
#define WS_NEEDED   339968

typedef __attribute__((ext_vector_type(16))) float float16v;
typedef _Float16 half8 __attribute__((ext_vector_type(8)));
union U4H8 { uint4 u; half8 h; };
union F4A  { float4 v; float f[4]; };
union F16V { float16v v; float f[16]; };
union HU   { _Float16 f; unsigned short u; };

__device__ __forceinline__ float fmed3(float a, float b, float c) {
  return __builtin_amdgcn_fmed3f(a, b, c);
}
__device__ __forceinline__ void gload16(const void* g, void* s) {
  __builtin_amdgcn_global_load_lds((const __attribute__((address_space(1))) unsigned int*)g,
                                   (__attribute__((address_space(3))) unsigned int*)s,
                                   16, 0, 0);
}

// ---------- fused prep (cnorm + zero) & pack (frag-linear fp16 of 1024*c) ----
// blocks [0,64): pack slot g = b*256+t; blocks [64,68): cnorm k = (b-64)*256+t.
// pack layout: g: mt=g>>9, s=(g>>6)&7, l=g&63 ; value j:
//   C[mt*32+(l&31)][s*16+(l>>5)*8+j]
__global__ __launch_bounds__(256) void vq_prep_pack(const float* __restrict__ C,
                                                    float* __restrict__ wsf,
                                                    uint4* __restrict__ PH) {
  const int b = blockIdx.x;
  if (b < 64) {
    int g = b * 256 + threadIdx.x;
    int mt = g >> 9, s = (g >> 6) & 7, l = g & 63;
    int cw = mt * 32 + (l & 31);
    int k0 = s * 16 + (l >> 5) * 8;
    const float* src = C + (size_t)cw * DIM + k0;
    float4 x0 = *(const float4*)src;
    float4 x1 = *(const float4*)(src + 4);
    unsigned h[8];
    {
      float v[8] = {x0.x, x0.y, x0.z, x0.w, x1.x, x1.y, x1.z, x1.w};
#pragma unroll
      for (int j = 0; j < 8; ++j) { HU u; u.f = (_Float16)(CSCALE * v[j]); h[j] = u.u; }
    }
    PH[g] = make_uint4(h[0] | (h[1] << 16), h[2] | (h[3] << 16),
                       h[4] | (h[5] << 16), h[6] | (h[7] << 16));
  } else {
    int k = (b - 64) * 256 + threadIdx.x;   // 4 blocks x 256 == 1024
    if (k == 0) { wsf[0] = 0.0f; ((unsigned*)wsf)[1] = 0u; }
    const float4* c4 = (const float4*)C + (size_t)k * DV;
    float s = 0.f;
#pragma unroll 8
    for (int i = 0; i < DV; ++i) {
      float4 v = c4[i];
      s = fmaf(v.x, v.x, s); s = fmaf(v.y, v.y, s);
      s = fmaf(v.z, v.z, s); s = fmaf(v.w, v.w, s);
    }
    wsf[WS_CNORM_F + k]  = s;
    wsf[WS_CN1024_F + k] = s * CSCALE;
  }
}

// ---------- main: 8-wave blocks, in-block split-K, in-block gather ----------
__global__ __launch_bounds__(512, 6) void vq_main14(const float* __restrict__ E,
                                                    const float* __restrict__ C,
                                                    float* __restrict__ wsf,
                                                    float* __restrict__ out) {
  __shared__ uint4 SH[2][1024];              // [buf][pair*512 + slot], 16KB/buf
  __shared__ __align__(16) float CN[1024];   // 1024*||c||^2
  __shared__ float X1[128], X2[128];         // cross-pair merge: best/second
  __shared__ int   XI[128];
  __shared__ int   BI[128];

  const int tid  = threadIdx.x;              // 0..511 (8 waves)
  const int w    = tid >> 6;                 // wave 0..7
  const int l    = tid & 63;
  const int half = l >> 5;
  const int rr   = l & 31;
  const int pair = w >> 2;                   // 0: k<512, 1: k>=512
  const int rw   = w & 3;                    // row sub-block 0..3
  const int row0 = blockIdx.x * 128;
  const int row  = row0 + rw * 32 + rr;

  const uint4* PHg = (const uint4*)((const char*)wsf + WS_PH_B);

  // ---- issue async stage of step-0 tiles (tg 0 and 16) + CN ----
  {
    uint4* base = &SH[0][0];
    gload16(PHg + tid,            base + tid);          // pair0 tile 0
    gload16(PHg + 16 * 512 + tid, base + 512 + tid);    // pair1 tile 16
    if (tid < 256)
      gload16(((const uint4*)(wsf + WS_CN1024_F)) + tid, ((uint4*)CN) + tid);
  }

  // ---- load this wave's 32 rows into register B-frags (single fp16 term) ----
  // lane (rr,half) covers dims {s*16 + half*8 .. +7} for s=0..7  (64 floats)
  half8 beh[8];
  float s2 = 0.f;
  const float* erow = E + (size_t)row * DIM + half * 8;
#pragma unroll
  for (int s = 0; s < 8; ++s) {
    float4 x0 = *(const float4*)(erow + s * 16);
    float4 x1 = *(const float4*)(erow + s * 16 + 4);
    float v[8] = {x0.x, x0.y, x0.z, x0.w, x1.x, x1.y, x1.z, x1.w};
#pragma unroll
    for (int j = 0; j < 8; ++j) {
      float y = v[j];
      s2 = fmaf(y, y, s2);
      beh[s][j] = (_Float16)(-2.f * y);
    }
  }

  asm volatile("s_waitcnt vmcnt(0)" ::: "memory");
  __syncthreads();

  float m1 = 3.0e38f, m2 = 3.0e38f;          // scaled best / second
  int   bi = 0;                              // best index (absolute)

  for (int st = 0; st < 16; ++st) {
    const int buf = st & 1;
    const int tg  = pair * 16 + st;
    // stage next step's two tiles (async; 1 gload16 per thread per tile)
    if (st < 15) {
      uint4* nb = &SH[buf ^ 1][0];
      const uint4* s0 = PHg + (size_t)(st + 1) * 512;
      const uint4* s1 = PHg + (size_t)(17 + st) * 512;
      gload16(s0 + tid, nb + tid);
      gload16(s1 + tid, nb + 512 + tid);
    }

    // two 4-deep MFMA chains; accA initialized with 1024*||c||^2
    F16V accA, accB;
#pragma unroll
    for (int q = 0; q < 4; ++q) {
      F4A c; c.v = *(const float4*)&CN[tg * 32 + q * 8 + half * 4];
      accA.f[q * 4 + 0] = c.f[0]; accA.f[q * 4 + 1] = c.f[1];
      accA.f[q * 4 + 2] = c.f[2]; accA.f[q * 4 + 3] = c.f[3];
    }
    accB.v = (float16v){0,0,0,0,0,0,0,0,0,0,0,0,0,0,0,0};
#pragma unroll
    for (int s = 0; s < 8; s += 2) {
      U4H8 h0, h1;
      h0.u = SH[buf][pair * 512 + s * 64 + l];
      h1.u = SH[buf][pair * 512 + (s + 1) * 64 + l];
      accA.v = __builtin_amdgcn_mfma_f32_32x32x16_f16(h0.h, beh[s],     accA.v, 0, 0, 0);
      accB.v = __builtin_amdgcn_mfma_f32_32x32x16_f16(h1.h, beh[s + 1], accB.v, 0, 0, 0);
    }

    // fold 16 scaled scores; k = tg*32 + half*4 + q*8 + i
    const int kb = tg * 32 + half * 4;
#pragma unroll
    for (int reg = 0; reg < 16; ++reg) {
      float sc = accA.f[reg] + accB.f[reg];
      bool nb_ = sc < m1;
      m2 = fmed3(sc, m1, m2);
      m1 = fminf(sc, m1);
      bi = nb_ ? (kb + (reg >> 2) * 8 + (reg & 3)) : bi;
    }

    asm volatile("s_waitcnt vmcnt(0)" ::: "memory");
    __syncthreads();
  }

  // ---- merge halves (lane l <-> l+32: same row, disjoint k subsets) ----
  {
    float om1 = __shfl_xor(m1, 32, 64);
    float om2 = __shfl_xor(m2, 32, 64);
    int   obi = __shfl_xor(bi, 32, 64);
    float nsv = fminf(fminf(m2, om2), fmaxf(m1, om1));
    if (om1 < m1 || (om1 == m1 && obi < bi)) { m1 = om1; bi = obi; }
    m2 = nsv;
  }
  float en = s2 + __shfl_xor(s2, 32, 64);

  // ---- cross-pair merge via LDS ----
  if (pair == 1 && half == 0) {
    X1[rw * 32 + rr] = m1; X2[rw * 32 + rr] = m2; XI[rw * 32 + rr] = bi;
  }
  __syncthreads();

  if (pair == 0 && half == 0) {
    const int r = rw * 32 + rr;
    float xb = X1[r], xs = X2[r];
    int   xi = XI[r];
    float sv = fminf(fminf(m2, xs), fmaxf(m1, xb));
    if (xb < m1 || (xb == m1 && xi < bi)) { m1 = xb; bi = xi; }
    out[row] = (float)bi;
    BI[r] = bi;
    if (sv - m1 < MARGINS) {
      unsigned idx = atomicAdd((unsigned*)wsf + 1, 1u);
      if (idx < FLAGCAP) ((int*)((char*)wsf + WS_LIST_B))[idx] = row;
    }
    float term = fmaf(m1, CDESCALE, en);
#pragma unroll
    for (int off = 16; off > 0; off >>= 1) term += __shfl_down(term, off);
    if (rr == 0) atomicAdd(wsf, term);
  }
  __syncthreads();

  // ---- gather quantized_st (128 rows x 32 float4) ----
  const float4* C4   = (const float4*)C;
  float4*       out4 = (float4*)out;
#pragma unroll
  for (int it = 0; it < 8; ++it) {
    int flat = it * 512 + tid;
    int r = flat >> 5, d4 = flat & 31;
    out4[(NROWS / 4) + (size_t)(row0 + r) * DV + d4] = C4[(size_t)BI[r] * DV + d4];
  }
}

// ---------- exact fp32 rescan of flagged rows (+ fused final scalars) --------
__global__ __launch_bounds__(256) void vq_fix(const float* __restrict__ E,
                                              const float* __restrict__ C,
                                              float* __restrict__ wsf,
                                              float* __restrict__ out) {
  __shared__ float4 eL[4][32];
  __shared__ float  RV[4][4];
  __shared__ int    RI[4][4];
  __shared__ int    RESi[4];
  const int tid = threadIdx.x;
  const int wv  = tid >> 6;
  const int ln  = tid & 63;

  // fused final scalars (wsf[0] complete after vq_main14)
  if (blockIdx.x == 0 && tid == 0) {
    float mse = wsf[0] / MSE_DENOM;
    out[NROWS + NROWS * DIM + 0] = 1.25f * mse;
    out[NROWS + NROWS * DIM + 1] = mse;
    out[NROWS + NROWS * DIM + 2] = mse;
  }

  const int* list = (const int*)((const char*)wsf + WS_LIST_B);
  int nf = (int)((const unsigned*)wsf)[1];
  if (nf > FLAGCAP) nf = FLAGCAP;
  const float4* E4 = (const float4*)E;
  const float4* C4 = (const float4*)C;
  const float*  cn = wsf + WS_CNORM_F;
  float4* out4 = (float4*)out;

  for (int g = blockIdx.x; g * 4 < nf; g += gridDim.x) {
    const int base = g * 4;
    if (tid < 128) {
      int r = tid >> 5, d4 = tid & 31;
      int R = (base + r < nf) ? list[base + r] : list[base];
      eL[r][d4] = E4[(size_t)R * DV + d4];
    }
    __syncthreads();
    float bv[4] = {3.0e38f, 3.0e38f, 3.0e38f, 3.0e38f};
    int   bi[4] = {0, 0, 0, 0};
#pragma unroll
    for (int j = 0; j < 4; ++j) {
      int k = j * 256 + tid;
      float d0 = 0.f, d1 = 0.f, d2 = 0.f, d3 = 0.f;
#pragma unroll 4
      for (int d4 = 0; d4 < 32; ++d4) {
        float4 c = C4[(size_t)k * DV + d4];
        float4 e0 = eL[0][d4], e1 = eL[1][d4], e2 = eL[2][d4], e3 = eL[3][d4];
        d0 = fmaf(c.x, e0.x, d0); d0 = fmaf(c.y, e0.y, d0);
        d0 = fmaf(c.z, e0.z, d0); d0 = fmaf(c.w, e0.w, d0);
        d1 = fmaf(c.x, e1.x, d1); d1 = fmaf(c.y, e1.y, d1);
        d1 = fmaf(c.z, e1.z, d1); d1 = fmaf(c.w, e1.w, d1);
        d2 = fmaf(c.x, e2.x, d2); d2 = fmaf(c.y, e2.y, d2);
        d2 = fmaf(c.z, e2.z, d2); d2 = fmaf(c.w, e2.w, d2);
        d3 = fmaf(c.x, e3.x, d3); d3 = fmaf(c.y, e3.y, d3);
        d3 = fmaf(c.z, e3.z, d3); d3 = fmaf(c.w, e3.w, d3);
      }
      float cnk = cn[k];
      float s0 = fmaf(-2.f, d0, cnk);
      float s1 = fmaf(-2.f, d1, cnk);
      float s2 = fmaf(-2.f, d2, cnk);
      float s3 = fmaf(-2.f, d3, cnk);
      if (s0 < bv[0] || (s0 == bv[0] && k < bi[0])) { bv[0] = s0; bi[0] = k; }
      if (s1 < bv[1] || (s1 == bv[1] && k < bi[1])) { bv[1] = s1; bi[1] = k; }
      if (s2 < bv[2] || (s2 == bv[2] && k < bi[2])) { bv[2] = s2; bi[2] = k; }
      if (s3 < bv[3] || (s3 == bv[3] && k < bi[3])) { bv[3] = s3; bi[3] = k; }
    }
#pragma unroll
    for (int off = 32; off > 0; off >>= 1) {
#pragma unroll
      for (int r = 0; r < 4; ++r) {
        float wv_ = __shfl_down(bv[r], off);
        int   ji  = __shfl_down(bi[r], off);
        if (wv_ < bv[r] || (wv_ == bv[r] && ji < bi[r])) { bv[r] = wv_; bi[r] = ji; }
      }
    }
    if (ln == 0) {
#pragma unroll
      for (int r = 0; r < 4; ++r) { RV[wv][r] = bv[r]; RI[wv][r] = bi[r]; }
    }
    __syncthreads();
    if (tid < 4) {
      float v = RV[0][tid]; int i = RI[0][tid];
#pragma unroll
      for (int q = 1; q < 4; ++q) {
        float vv = RV[q][tid]; int ii = RI[q][tid];
        if (vv < v || (vv == v && ii < i)) { v = vv; i = ii; }
      }
      RESi[tid] = i;
      if (base + tid < nf) out[list[base + tid]] = (float)i;
    }
    __syncthreads();
    if (tid < 128) {
      int r = tid >> 5, d4 = tid & 31;
      if (base + r < nf) {
        int R = list[base + r];
        out4[(NROWS / 4) + (size_t)R * DV + d4] = C4[(size_t)RESi[r] * DV + d4];
      }
    }
    __syncthreads();
  }
}

// ================= fallback (round-1 fp32 path, used if ws too small) ==========
__global__ __launch_bounds__(256) void vq_prep_fb(const float* __restrict__ C,
                                                  float* __restrict__ ws) {
  int k = blockIdx.x * 256 + threadIdx.x;
  if (k == 0) ws[0] = 0.0f;
  const float4* c4 = (const float4*)C + (size_t)k * DV;
  float s = 0.f;
#pragma unroll 8
  for (int i = 0; i < DV; ++i) {
    float4 v = c4[i];
    s = fmaf(v.x, v.x, s); s = fmaf(v.y, v.y, s);
    s = fmaf(v.z, v.z, s); s = fmaf(v.w, v.w, s);
  }
  ws[64 + k] = s;
}

__global__ __launch_bounds__(256) void vq_main_fb(const float* __restrict__ E,
                                                  const float* __restrict__ C,
                                                  const float* __restrict__ cnorm,
                                                  float* __restrict__ out,
                                                  float* __restrict__ lossacc) {
  __shared__ float smem[16384];
  float4* EsV = (float4*)smem;
  float4* CsV = (float4*)(smem + 8192);
  const int tid  = threadIdx.x;
  const int row0 = blockIdx.x * 64;
#pragma unroll
  for (int i = 0; i < 8; ++i) {
    int flat = i * 256 + tid;
    int r = flat >> 5, d4 = flat & 31;
    EsV[r * 32 + (d4 ^ (r & 31))] = ((const float4*)E)[(size_t)(row0 + r) * DV + d4];
  }
  const int tx = tid & 15, ty = tid >> 4;
  int rbase[4], rmask[4];
#pragma unroll
  for (int i = 0; i < 4; ++i) { int r = i * 16 + ty; rbase[i] = r * 32; rmask[i] = r & 31; }
  float bestv[4]; int besti[4];
#pragma unroll
  for (int i = 0; i < 4; ++i) { bestv[i] = 3.0e38f; besti[i] = 0; }
  for (int ch = 0; ch < 16; ++ch) {
    const int k0 = ch * 64;
    __syncthreads();
#pragma unroll
    for (int i = 0; i < 8; ++i) {
      int flat = i * 256 + tid;
      int k = flat >> 5, d4 = flat & 31;
      CsV[k * 32 + (d4 ^ (k & 31))] = ((const float4*)C)[(size_t)(k0 + k) * DV + d4];
    }
    __syncthreads();
    float acc[4][4] = {};
#pragma unroll 8
    for (int d4 = 0; d4 < DV; ++d4) {
      float4 a[4], b[4];
#pragma unroll
      for (int i = 0; i < 4; ++i) a[i] = EsV[rbase[i] + (d4 ^ rmask[i])];
#pragma unroll
      for (int j = 0; j < 4; ++j) { int k = j * 16 + tx; b[j] = CsV[k * 32 + (d4 ^ (k & 31))]; }
#pragma unroll
      for (int i = 0; i < 4; ++i)
#pragma unroll
        for (int j = 0; j < 4; ++j) {
          acc[i][j] = fmaf(a[i].x, b[j].x, acc[i][j]);
          acc[i][j] = fmaf(a[i].y, b[j].y, acc[i][j]);
          acc[i][j] = fmaf(a[i].z, b[j].z, acc[i][j]);
          acc[i][j] = fmaf(a[i].w, b[j].w, acc[i][j]);
        }
    }
#pragma unroll
    for (int j = 0; j < 4; ++j) {
      int kg = k0 + j * 16 + tx;
      float cnv = cnorm[kg];
#pragma unroll
      for (int i = 0; i < 4; ++i) {
        float s = fmaf(-2.0f, acc[i][j], cnv);
        if (s < bestv[i] || (s == bestv[i] && kg < besti[i])) { bestv[i] = s; besti[i] = kg; }
      }
    }
  }
  float* Rv = smem + 8192;
  int*   Ri = (int*)(smem + 9216);
  int*   BIf = (int*)(smem + 10240);
  __syncthreads();
#pragma unroll
  for (int i = 0; i < 4; ++i) {
    int r = i * 16 + ty;
    Rv[r * 16 + tx] = bestv[i];
    Ri[r * 16 + tx] = besti[i];
  }
  __syncthreads();
  if (tid < 64) {
    const int r = tid;
    float bv = Rv[r * 16]; int bi = Ri[r * 16];
#pragma unroll
    for (int t = 1; t < 16; ++t) {
      float v = Rv[r * 16 + t]; int ii = Ri[r * 16 + t];
      if (v < bv || (v == bv && ii < bi)) { bv = v; bi = ii; }
    }
    float en = 0.f;
#pragma unroll 8
    for (int d4 = 0; d4 < DV; ++d4) {
      float4 v = EsV[r * 32 + (d4 ^ (r & 31))];
      en = fmaf(v.x, v.x, en); en = fmaf(v.y, v.y, en);
      en = fmaf(v.z, v.z, en); en = fmaf(v.w, v.w, en);
    }
    out[row0 + r] = (float)bi;
    BIf[r] = bi;
    float blocksum = en + bv;
#pragma unroll
    for (int off = 32; off > 0; off >>= 1) blocksum += __shfl_down(blocksum, off);
    if (tid == 0) atomicAdd(lossacc, blocksum);
  }
  __syncthreads();
  const float4* C4   = (const float4*)C;
  float4*       out4 = (float4*)out;
  for (int flat = tid; flat < 64 * DV; flat += 256) {
    int r = flat >> 5, d4 = flat & 31;
    out4[(NROWS / 4) + (size_t)(row0 + r) * DV + d4] = C4[(size_t)BIf[r] * DV + d4];
  }
}

__global__ void vq_final_fb(const float* __restrict__ ws, float* __restrict__ out) {
  if (threadIdx.x == 0 && blockIdx.x == 0) {
    float mse = ws[0] / MSE_DENOM;
    out[NROWS + NROWS * DIM + 0] = 1.25f * mse;
    out[NROWS + NROWS * DIM + 1] = mse;
    out[NROWS + NROWS * DIM + 2] = mse;
  }
}

extern "C" void kernel_launch(void* const* d_in, const int* in_sizes, int n_in,
                              void* d_out, int out_size, void* d_ws, size_t ws_size,
                              hipStream_t stream) {
  const float* E = (const float*)d_in[0];
  const float* C = (const float*)d_in[1];
  float* out = (float*)d_out;
  float* wsf = (float*)d_ws;

  if (ws_size >= (size_t)WS_NEEDED) {
    uint4* PH = (uint4*)((char*)d_ws + WS_PH_B);
    vq_prep_pack<<<68, 256, 0, stream>>>(C, wsf, PH);
    vq_main14<<<NROWS / 128, 512, 0, stream>>>(E, C, wsf, out);
    vq_fix<<<512, 256, 0, stream>>>(E, C, wsf, out);
  } else {
    vq_prep_fb<<<4, 256, 0, stream>>>(C, wsf);
    vq_main_fb<<<NROWS / 64, 256, 0, stream>>>(E, C, wsf + 64, out, wsf);
    vq_final_fb<<<1, 64, 0, stream>>>(wsf, out);
  }
}

// Round 14
// 158.116 us; speedup vs baseline: 1.2286x; 1.0526x over previous
//
#include <hip/hip_runtime.h>

// VectorQuantizer, single-term fp16 MFMA, in-block split-K, 4-wave blocks.
// FINAL CONSOLIDATION == round-11 session best (159.5us total; main 61-63us).
// 512-thread variants (rounds 12/13) spill on hipcc (VGPR 32/40, WRITE +20-40MB)
// -> 256-thread shape is the stable optimum (VGPR 60, clean traffic).
// scores = -2*E@C^T + ||c||^2; argmin_k; gather; mse losses.
//   eh = fp16(-2e), ch = fp16(1024c); acc = eh@ch (fp32 MFMA, C-init = 1024*||c||^2)
//   scaled score = acc ; real = acc * 2^-10. Dropped-term err sigma ~3e-6 << MARGIN.
// Block = 256 thr (4 waves) x 64 rows; grid 1024 -> 4 blocks/CU, 16 waves/CU.
// Wave-pair 0 sweeps k<512, pair 1 k>=512; cross-pair merge via LDS at the end.
// Codebook tiles stream via global_load_lds (16KB/step), dbuf'd, 16 steps.
// Rows whose top-2 gap < MARGIN get an exact fp32 rescan (vq_fix, 4 rows/sweep).
// Output: [0,N) idx as float | [N,N+N*D) quantized | +0,1,2 = vq,embed,commit.

#define NROWS 65536
#define KCB   1024
#define DIM   128
#define DV    32
#define MSE_DENOM 8388608.0f
#define MARGIN 3.0e-5f
#define MARGINS 0.030720f   // MARGIN * 1024 (scaled domain)
#define FLAGCAP 16384
#define CSCALE   1024.0f
#define CDESCALE 0.0009765625f

// ws byte layout
#define WS_CNORM_F  256     // float index: raw cnorm[1024] at byte 1024
#define WS_CN1024_F 1280    // float index: 1024*cnorm[1024] at byte 5120
#define WS_LIST_B   12288   // 16384 ints
#define WS_PH_B     77824   // 262144 B packed codebook frags (fp16)
#define WS_NEEDED   339968

typedef __attribute__((ext_vector_type(16))) float float16v;
typedef _Float16 half8 __attribute__((ext_vector_type(8)));
union U4H8 { uint4 u; half8 h; };
union F4A  { float4 v; float f[4]; };
union F16V { float16v v; float f[16]; };
union HU   { _Float16 f; unsigned short u; };

__device__ __forceinline__ float fmed3(float a, float b, float c) {
  return __builtin_amdgcn_fmed3f(a, b, c);
}
__device__ __forceinline__ void gload16(const void* g, void* s) {
  __builtin_amdgcn_global_load_lds((const __attribute__((address_space(1))) unsigned int*)g,
                                   (__attribute__((address_space(3))) unsigned int*)s,
                                   16, 0, 0);
}

// ---------- fused prep (cnorm + zero) & pack (frag-linear fp16 of 1024*c) ----
// blocks [0,64): pack slot g = b*256+t; blocks [64,68): cnorm k = (b-64)*256+t.
// pack layout: g: mt=g>>9, s=(g>>6)&7, l=g&63 ; value j:
//   C[mt*32+(l&31)][s*16+(l>>5)*8+j]
__global__ __launch_bounds__(256) void vq_prep_pack(const float* __restrict__ C,
                                                    float* __restrict__ wsf,
                                                    uint4* __restrict__ PH) {
  const int b = blockIdx.x;
  if (b < 64) {
    int g = b * 256 + threadIdx.x;
    int mt = g >> 9, s = (g >> 6) & 7, l = g & 63;
    int cw = mt * 32 + (l & 31);
    int k0 = s * 16 + (l >> 5) * 8;
    const float* src = C + (size_t)cw * DIM + k0;
    float4 x0 = *(const float4*)src;
    float4 x1 = *(const float4*)(src + 4);
    unsigned h[8];
    {
      float v[8] = {x0.x, x0.y, x0.z, x0.w, x1.x, x1.y, x1.z, x1.w};
#pragma unroll
      for (int j = 0; j < 8; ++j) { HU u; u.f = (_Float16)(CSCALE * v[j]); h[j] = u.u; }
    }
    PH[g] = make_uint4(h[0] | (h[1] << 16), h[2] | (h[3] << 16),
                       h[4] | (h[5] << 16), h[6] | (h[7] << 16));
  } else {
    int k = (b - 64) * 256 + threadIdx.x;   // 4 blocks x 256 == 1024
    if (k == 0) { wsf[0] = 0.0f; ((unsigned*)wsf)[1] = 0u; }
    const float4* c4 = (const float4*)C + (size_t)k * DV;
    float s = 0.f;
#pragma unroll 8
    for (int i = 0; i < DV; ++i) {
      float4 v = c4[i];
      s = fmaf(v.x, v.x, s); s = fmaf(v.y, v.y, s);
      s = fmaf(v.z, v.z, s); s = fmaf(v.w, v.w, s);
    }
    wsf[WS_CNORM_F + k]  = s;
    wsf[WS_CN1024_F + k] = s * CSCALE;
  }
}

// ---------- main: 4-wave blocks, in-block split-K, in-block gather ----------
__global__ __launch_bounds__(256, 4) void vq_main8(const float* __restrict__ E,
                                                   const float* __restrict__ C,
                                                   float* __restrict__ wsf,
                                                   float* __restrict__ out) {
  __shared__ uint4 SH[2][1024];              // [buf][pair*512 + slot], 16KB/buf
  __shared__ __align__(16) float CN[1024];   // 1024*||c||^2
  __shared__ float X1[64], X2[64];           // cross-pair merge: best/second
  __shared__ int   XI[64];
  __shared__ int   BI[64];

  const int tid  = threadIdx.x;              // 0..255 (4 waves)
  const int w    = tid >> 6;                 // wave 0..3
  const int l    = tid & 63;
  const int half = l >> 5;
  const int rr   = l & 31;
  const int pair = w >> 1;                   // 0: k<512, 1: k>=512
  const int rw   = w & 1;                    // row sub-block 0/1
  const int row0 = blockIdx.x * 64;
  const int row  = row0 + rw * 32 + rr;

  const uint4* PHg = (const uint4*)((const char*)wsf + WS_PH_B);

  // ---- issue async stage of step-0 tiles (tg 0 and 16) + CN ----
  {
    uint4* base = &SH[0][0];
    gload16(PHg + tid,                  base + tid);
    gload16(PHg + 256 + tid,            base + 256 + tid);
    gload16(PHg + 16 * 512 + tid,       base + 512 + tid);
    gload16(PHg + 16 * 512 + 256 + tid, base + 768 + tid);
    gload16(((const uint4*)(wsf + WS_CN1024_F)) + tid, ((uint4*)CN) + tid);
  }

  // ---- load this wave's 32 rows into register B-frags (single fp16 term) ----
  // lane (rr,half) covers dims {s*16 + half*8 .. +7} for s=0..7  (64 floats)
  half8 beh[8];
  float s2 = 0.f;
  const float* erow = E + (size_t)row * DIM + half * 8;
#pragma unroll
  for (int s = 0; s < 8; ++s) {
    float4 x0 = *(const float4*)(erow + s * 16);
    float4 x1 = *(const float4*)(erow + s * 16 + 4);
    float v[8] = {x0.x, x0.y, x0.z, x0.w, x1.x, x1.y, x1.z, x1.w};
#pragma unroll
    for (int j = 0; j < 8; ++j) {
      float y = v[j];
      s2 = fmaf(y, y, s2);
      beh[s][j] = (_Float16)(-2.f * y);
    }
  }

  asm volatile("s_waitcnt vmcnt(0)" ::: "memory");
  __syncthreads();

  float m1 = 3.0e38f, m2 = 3.0e38f;          // scaled best / second
  int   bi = 0;                              // best index (absolute)

  for (int st = 0; st < 16; ++st) {
    const int buf = st & 1;
    const int tg  = pair * 16 + st;
    // stage next step's two tiles (async)
    if (st < 15) {
      uint4* nb = &SH[buf ^ 1][0];
      const uint4* s0 = PHg + (size_t)(st + 1) * 512;
      const uint4* s1 = PHg + (size_t)(17 + st) * 512;
      gload16(s0 + tid,       nb + tid);
      gload16(s0 + 256 + tid, nb + 256 + tid);
      gload16(s1 + tid,       nb + 512 + tid);
      gload16(s1 + 256 + tid, nb + 768 + tid);
    }

    // two 4-deep MFMA chains; accA initialized with 1024*||c||^2
    F16V accA, accB;
#pragma unroll
    for (int q = 0; q < 4; ++q) {
      F4A c; c.v = *(const float4*)&CN[tg * 32 + q * 8 + half * 4];
      accA.f[q * 4 + 0] = c.f[0]; accA.f[q * 4 + 1] = c.f[1];
      accA.f[q * 4 + 2] = c.f[2]; accA.f[q * 4 + 3] = c.f[3];
    }
    accB.v = (float16v){0,0,0,0,0,0,0,0,0,0,0,0,0,0,0,0};
#pragma unroll
    for (int s = 0; s < 8; s += 2) {
      U4H8 h0, h1;
      h0.u = SH[buf][pair * 512 + s * 64 + l];
      h1.u = SH[buf][pair * 512 + (s + 1) * 64 + l];
      accA.v = __builtin_amdgcn_mfma_f32_32x32x16_f16(h0.h, beh[s],     accA.v, 0, 0, 0);
      accB.v = __builtin_amdgcn_mfma_f32_32x32x16_f16(h1.h, beh[s + 1], accB.v, 0, 0, 0);
    }

    // fold 16 scaled scores; k = tg*32 + half*4 + q*8 + i
    const int kb = tg * 32 + half * 4;
#pragma unroll
    for (int reg = 0; reg < 16; ++reg) {
      float sc = accA.f[reg] + accB.f[reg];
      bool nb_ = sc < m1;
      m2 = fmed3(sc, m1, m2);
      m1 = fminf(sc, m1);
      bi = nb_ ? (kb + (reg >> 2) * 8 + (reg & 3)) : bi;
    }

    asm volatile("s_waitcnt vmcnt(0)" ::: "memory");
    __syncthreads();
  }

  // ---- merge halves (lane l <-> l+32: same row, disjoint k subsets) ----
  {
    float om1 = __shfl_xor(m1, 32, 64);
    float om2 = __shfl_xor(m2, 32, 64);
    int   obi = __shfl_xor(bi, 32, 64);
    float nsv = fminf(fminf(m2, om2), fmaxf(m1, om1));
    if (om1 < m1 || (om1 == m1 && obi < bi)) { m1 = om1; bi = obi; }
    m2 = nsv;
  }
  float en = s2 + __shfl_xor(s2, 32, 64);

  // ---- cross-pair merge via LDS ----
  if (pair == 1 && half == 0) {
    X1[rw * 32 + rr] = m1; X2[rw * 32 + rr] = m2; XI[rw * 32 + rr] = bi;
  }
  __syncthreads();

  if (pair == 0 && half == 0) {
    const int r = rw * 32 + rr;
    float xb = X1[r], xs = X2[r];
    int   xi = XI[r];
    float sv = fminf(fminf(m2, xs), fmaxf(m1, xb));
    if (xb < m1 || (xb == m1 && xi < bi)) { m1 = xb; bi = xi; }
    out[row] = (float)bi;
    BI[r] = bi;
    if (sv - m1 < MARGINS) {
      unsigned idx = atomicAdd((unsigned*)wsf + 1, 1u);
      if (idx < FLAGCAP) ((int*)((char*)wsf + WS_LIST_B))[idx] = row;
    }
    float term = fmaf(m1, CDESCALE, en);
#pragma unroll
    for (int off = 16; off > 0; off >>= 1) term += __shfl_down(term, off);
    if (rr == 0) atomicAdd(wsf, term);
  }
  __syncthreads();

  // ---- gather quantized_st ----
  const float4* C4   = (const float4*)C;
  float4*       out4 = (float4*)out;
#pragma unroll
  for (int it = 0; it < 8; ++it) {
    int flat = it * 256 + tid;
    int r = flat >> 5, d4 = flat & 31;
    out4[(NROWS / 4) + (size_t)(row0 + r) * DV + d4] = C4[(size_t)BI[r] * DV + d4];
  }
}

// ---------- exact fp32 rescan of flagged rows (+ fused final scalars) --------
__global__ __launch_bounds__(256) void vq_fix(const float* __restrict__ E,
                                              const float* __restrict__ C,
                                              float* __restrict__ wsf,
                                              float* __restrict__ out) {
  __shared__ float4 eL[4][32];
  __shared__ float  RV[4][4];
  __shared__ int    RI[4][4];
  __shared__ int    RESi[4];
  const int tid = threadIdx.x;
  const int wv  = tid >> 6;
  const int ln  = tid & 63;

  // fused final scalars (wsf[0] complete after vq_main8)
  if (blockIdx.x == 0 && tid == 0) {
    float mse = wsf[0] / MSE_DENOM;
    out[NROWS + NROWS * DIM + 0] = 1.25f * mse;
    out[NROWS + NROWS * DIM + 1] = mse;
    out[NROWS + NROWS * DIM + 2] = mse;
  }

  const int* list = (const int*)((const char*)wsf + WS_LIST_B);
  int nf = (int)((const unsigned*)wsf)[1];
  if (nf > FLAGCAP) nf = FLAGCAP;
  const float4* E4 = (const float4*)E;
  const float4* C4 = (const float4*)C;
  const float*  cn = wsf + WS_CNORM_F;
  float4* out4 = (float4*)out;

  for (int g = blockIdx.x; g * 4 < nf; g += gridDim.x) {
    const int base = g * 4;
    if (tid < 128) {
      int r = tid >> 5, d4 = tid & 31;
      int R = (base + r < nf) ? list[base + r] : list[base];
      eL[r][d4] = E4[(size_t)R * DV + d4];
    }
    __syncthreads();
    float bv[4] = {3.0e38f, 3.0e38f, 3.0e38f, 3.0e38f};
    int   bi[4] = {0, 0, 0, 0};
#pragma unroll
    for (int j = 0; j < 4; ++j) {
      int k = j * 256 + tid;
      float d0 = 0.f, d1 = 0.f, d2 = 0.f, d3 = 0.f;
#pragma unroll 4
      for (int d4 = 0; d4 < 32; ++d4) {
        float4 c = C4[(size_t)k * DV + d4];
        float4 e0 = eL[0][d4], e1 = eL[1][d4], e2 = eL[2][d4], e3 = eL[3][d4];
        d0 = fmaf(c.x, e0.x, d0); d0 = fmaf(c.y, e0.y, d0);
        d0 = fmaf(c.z, e0.z, d0); d0 = fmaf(c.w, e0.w, d0);
        d1 = fmaf(c.x, e1.x, d1); d1 = fmaf(c.y, e1.y, d1);
        d1 = fmaf(c.z, e1.z, d1); d1 = fmaf(c.w, e1.w, d1);
        d2 = fmaf(c.x, e2.x, d2); d2 = fmaf(c.y, e2.y, d2);
        d2 = fmaf(c.z, e2.z, d2); d2 = fmaf(c.w, e2.w, d2);
        d3 = fmaf(c.x, e3.x, d3); d3 = fmaf(c.z, e3.z, d3);
        d3 = fmaf(c.y, e3.y, d3); d3 = fmaf(c.w, e3.w, d3);
      }
      float cnk = cn[k];
      float s0 = fmaf(-2.f, d0, cnk);
      float s1 = fmaf(-2.f, d1, cnk);
      float s2 = fmaf(-2.f, d2, cnk);
      float s3 = fmaf(-2.f, d3, cnk);
      if (s0 < bv[0] || (s0 == bv[0] && k < bi[0])) { bv[0] = s0; bi[0] = k; }
      if (s1 < bv[1] || (s1 == bv[1] && k < bi[1])) { bv[1] = s1; bi[1] = k; }
      if (s2 < bv[2] || (s2 == bv[2] && k < bi[2])) { bv[2] = s2; bi[2] = k; }
      if (s3 < bv[3] || (s3 == bv[3] && k < bi[3])) { bv[3] = s3; bi[3] = k; }
    }
#pragma unroll
    for (int off = 32; off > 0; off >>= 1) {
#pragma unroll
      for (int r = 0; r < 4; ++r) {
        float wv_ = __shfl_down(bv[r], off);
        int   ji  = __shfl_down(bi[r], off);
        if (wv_ < bv[r] || (wv_ == bv[r] && ji < bi[r])) { bv[r] = wv_; bi[r] = ji; }
      }
    }
    if (ln == 0) {
#pragma unroll
      for (int r = 0; r < 4; ++r) { RV[wv][r] = bv[r]; RI[wv][r] = bi[r]; }
    }
    __syncthreads();
    if (tid < 4) {
      float v = RV[0][tid]; int i = RI[0][tid];
#pragma unroll
      for (int q = 1; q < 4; ++q) {
        float vv = RV[q][tid]; int ii = RI[q][tid];
        if (vv < v || (vv == v && ii < i)) { v = vv; i = ii; }
      }
      RESi[tid] = i;
      if (base + tid < nf) out[list[base + tid]] = (float)i;
    }
    __syncthreads();
    if (tid < 128) {
      int r = tid >> 5, d4 = tid & 31;
      if (base + r < nf) {
        int R = list[base + r];
        out4[(NROWS / 4) + (size_t)R * DV + d4] = C4[(size_t)RESi[r] * DV + d4];
      }
    }
    __syncthreads();
  }
}

// ================= fallback (round-1 fp32 path, used if ws too small) ==========
__global__ __launch_bounds__(256) void vq_prep_fb(const float* __restrict__ C,
                                                  float* __restrict__ ws) {
  int k = blockIdx.x * 256 + threadIdx.x;
  if (k == 0) ws[0] = 0.0f;
  const float4* c4 = (const float4*)C + (size_t)k * DV;
  float s = 0.f;
#pragma unroll 8
  for (int i = 0; i < DV; ++i) {
    float4 v = c4[i];
    s = fmaf(v.x, v.x, s); s = fmaf(v.y, v.y, s);
    s = fmaf(v.z, v.z, s); s = fmaf(v.w, v.w, s);
  }
  ws[64 + k] = s;
}

__global__ __launch_bounds__(256) void vq_main_fb(const float* __restrict__ E,
                                                  const float* __restrict__ C,
                                                  const float* __restrict__ cnorm,
                                                  float* __restrict__ out,
                                                  float* __restrict__ lossacc) {
  __shared__ float smem[16384];
  float4* EsV = (float4*)smem;
  float4* CsV = (float4*)(smem + 8192);
  const int tid  = threadIdx.x;
  const int row0 = blockIdx.x * 64;
#pragma unroll
  for (int i = 0; i < 8; ++i) {
    int flat = i * 256 + tid;
    int r = flat >> 5, d4 = flat & 31;
    EsV[r * 32 + (d4 ^ (r & 31))] = ((const float4*)E)[(size_t)(row0 + r) * DV + d4];
  }
  const int tx = tid & 15, ty = tid >> 4;
  int rbase[4], rmask[4];
#pragma unroll
  for (int i = 0; i < 4; ++i) { int r = i * 16 + ty; rbase[i] = r * 32; rmask[i] = r & 31; }
  float bestv[4]; int besti[4];
#pragma unroll
  for (int i = 0; i < 4; ++i) { bestv[i] = 3.0e38f; besti[i] = 0; }
  for (int ch = 0; ch < 16; ++ch) {
    const int k0 = ch * 64;
    __syncthreads();
#pragma unroll
    for (int i = 0; i < 8; ++i) {
      int flat = i * 256 + tid;
      int k = flat >> 5, d4 = flat & 31;
      CsV[k * 32 + (d4 ^ (k & 31))] = ((const float4*)C)[(size_t)(k0 + k) * DV + d4];
    }
    __syncthreads();
    float acc[4][4] = {};
#pragma unroll 8
    for (int d4 = 0; d4 < DV; ++d4) {
      float4 a[4], b[4];
#pragma unroll
      for (int i = 0; i < 4; ++i) a[i] = EsV[rbase[i] + (d4 ^ rmask[i])];
#pragma unroll
      for (int j = 0; j < 4; ++j) { int k = j * 16 + tx; b[j] = CsV[k * 32 + (d4 ^ (k & 31))]; }
#pragma unroll
      for (int i = 0; i < 4; ++i)
#pragma unroll
        for (int j = 0; j < 4; ++j) {
          acc[i][j] = fmaf(a[i].x, b[j].x, acc[i][j]);
          acc[i][j] = fmaf(a[i].y, b[j].y, acc[i][j]);
          acc[i][j] = fmaf(a[i].z, b[j].z, acc[i][j]);
          acc[i][j] = fmaf(a[i].w, b[j].w, acc[i][j]);
        }
    }
#pragma unroll
    for (int j = 0; j < 4; ++j) {
      int kg = k0 + j * 16 + tx;
      float cnv = cnorm[kg];
#pragma unroll
      for (int i = 0; i < 4; ++i) {
        float s = fmaf(-2.0f, acc[i][j], cnv);
        if (s < bestv[i] || (s == bestv[i] && kg < besti[i])) { bestv[i] = s; besti[i] = kg; }
      }
    }
  }
  float* Rv = smem + 8192;
  int*   Ri = (int*)(smem + 9216);
  int*   BIf = (int*)(smem + 10240);
  __syncthreads();
#pragma unroll
  for (int i = 0; i < 4; ++i) {
    int r = i * 16 + ty;
    Rv[r * 16 + tx] = bestv[i];
    Ri[r * 16 + tx] = besti[i];
  }
  __syncthreads();
  if (tid < 64) {
    const int r = tid;
    float bv = Rv[r * 16]; int bi = Ri[r * 16];
#pragma unroll
    for (int t = 1; t < 16; ++t) {
      float v = Rv[r * 16 + t]; int ii = Ri[r * 16 + t];
      if (v < bv || (v == bv && ii < bi)) { bv = v; bi = ii; }
    }
    float en = 0.f;
#pragma unroll 8
    for (int d4 = 0; d4 < DV; ++d4) {
      float4 v = EsV[r * 32 + (d4 ^ (r & 31))];
      en = fmaf(v.x, v.x, en); en = fmaf(v.y, v.y, en);
      en = fmaf(v.z, v.z, en); en = fmaf(v.w, v.w, en);
    }
    out[row0 + r] = (float)bi;
    BIf[r] = bi;
    float blocksum = en + bv;
#pragma unroll
    for (int off = 32; off > 0; off >>= 1) blocksum += __shfl_down(blocksum, off);
    if (tid == 0) atomicAdd(lossacc, blocksum);
  }
  __syncthreads();
  const float4* C4   = (const float4*)C;
  float4*       out4 = (float4*)out;
  for (int flat = tid; flat < 64 * DV; flat += 256) {
    int r = flat >> 5, d4 = flat & 31;
    out4[(NROWS / 4) + (size_t)(row0 + r) * DV + d4] = C4[(size_t)BIf[r] * DV + d4];
  }
}

__global__ void vq_final_fb(const float* __restrict__ ws, float* __restrict__ out) {
  if (threadIdx.x == 0 && blockIdx.x == 0) {
    float mse = ws[0] / MSE_DENOM;
    out[NROWS + NROWS * DIM + 0] = 1.25f * mse;
    out[NROWS + NROWS * DIM + 1] = mse;
    out[NROWS + NROWS * DIM + 2] = mse;
  }
}

extern "C" void kernel_launch(void* const* d_in, const int* in_sizes, int n_in,
                              void* d_out, int out_size, void* d_ws, size_t ws_size,
                              hipStream_t stream) {
  const float* E = (const float*)d_in[0];
  const float* C = (const float*)d_in[1];
  float* out = (float*)d_out;
  float* wsf = (float*)d_ws;

  if (ws_size >= (size_t)WS_NEEDED) {
    uint4* PH = (uint4*)((char*)d_ws + WS_PH_B);
    vq_prep_pack<<<68, 256, 0, stream>>>(C, wsf, PH);
    vq_main8<<<NROWS / 64, 256, 0, stream>>>(E, C, wsf, out);
    vq_fix<<<512, 256, 0, stream>>>(E, C, wsf, out);
  } else {
    vq_prep_fb<<<4, 256, 0, stream>>>(C, wsf);
    vq_main_fb<<<NROWS / 64, 256, 0, stream>>>(E, C, wsf + 64, out, wsf);
    vq_final_fb<<<1, 64, 0, stream>>>(wsf, out);
  }
}